// Round 1
// baseline (58.550 us; speedup 1.0000x reference)
//
#include <hip/hip_runtime.h>

#define NPTS 8192
#define KNN  15
#define WPB  8                // waves (= queries) per block
#define TPB  (WPB * 64)       // 512 threads

// Ascending bitonic sort of one u32 per lane across a 64-lane wave.
__device__ __forceinline__ unsigned int bitonic_sort_u32(unsigned int v, int lane) {
#pragma unroll
  for (int k = 2; k <= 64; k <<= 1) {
#pragma unroll
    for (int j = k >> 1; j > 0; j >>= 1) {
      unsigned int o = __shfl_xor(v, j, 64);
      bool keep_min = ((lane & k) == 0) == ((lane & j) == 0);
      unsigned int lo = (v < o) ? v : o;
      unsigned int hi = (v < o) ? o : v;
      v = keep_min ? lo : hi;
    }
  }
  return v;
}

// Ascending bitonic sort of one u64 per lane across a 64-lane wave.
__device__ __forceinline__ unsigned long long bitonic_sort_u64(unsigned long long v, int lane) {
#pragma unroll
  for (int k = 2; k <= 64; k <<= 1) {
#pragma unroll
    for (int j = k >> 1; j > 0; j >>= 1) {
      unsigned long long o = __shfl_xor(v, j, 64);
      bool keep_min = ((lane & k) == 0) == ((lane & j) == 0);
      unsigned long long lo = (v < o) ? v : o;
      unsigned long long hi = (v < o) ? o : v;
      v = keep_min ? lo : hi;
    }
  }
  return v;
}

__global__ __launch_bounds__(TPB)
void knn_kernel(const float* __restrict__ x, const int* __restrict__ y,
                float* __restrict__ out) {
  __shared__ float4 sx4[NPTS / 2];                 // 64 KB: all points, (x0,y0,x1,y1) pairs
  __shared__ unsigned int ybits[NPTS / 32];        // 1 KB label bitset
  __shared__ unsigned long long buf[WPB][64];      // 4 KB collect buffers
  __shared__ int cnt[WPB];

  const int tid = threadIdx.x;

  // ---- stage x (coalesced float4) and y (bitset) into LDS ----
  const float4* gx4 = (const float4*)x;
#pragma unroll
  for (int i = tid; i < NPTS / 2; i += TPB) sx4[i] = gx4[i];
  if (tid < NPTS / 32) {
    unsigned int b = 0;
    const int* yy = y + (tid << 5);
#pragma unroll
    for (int k2 = 0; k2 < 32; ++k2) b |= ((unsigned int)(yy[k2] & 1)) << k2;
    ybits[tid] = b;
  }
  if (tid < WPB) cnt[tid] = 0;
  __syncthreads();

  const int w = tid >> 6;
  const int lane = tid & 63;
  const int q = (int)blockIdx.x * WPB + w;
  const float2 xq = ((const float2*)sx4)[q];

  // ---- pass 1: per-lane min distance over its 128-candidate stripe ----
  const float BIG = 3.0e38f;
  float m1 = BIG;
#pragma unroll 4
  for (int s = 0; s < 64; ++s) {
    float4 p = sx4[(s << 6) + lane];
    int j0 = ((s << 6) + lane) << 1;
    float dx0 = xq.x - p.x, dy0 = xq.y - p.y;
    float dx1 = xq.x - p.z, dy1 = xq.y - p.w;
    float d0 = dx0 * dx0 + dy0 * dy0;
    float d1 = dx1 * dx1 + dy1 * dy1;
    d0 = (j0 == q) ? BIG : d0;          // exclude self
    d1 = (j0 + 1 == q) ? BIG : d1;
    m1 = fminf(m1, fminf(d0, d1));
  }

  // 15th smallest of the 64 lane minima = upper bound on true 15th distance.
  unsigned int srt = bitonic_sort_u32(__float_as_uint(m1), lane);
  float T = __uint_as_float(__shfl(srt, KNN - 1, 64));
  float Tpad = T * (1.0f + 1.0e-5f) + 1.0e-30f;   // margin >> fp32 eval noise (2.4e-7 rel)

  // ---- pass 2: collect all candidates with d32 <= Tpad; exact fp64 keys ----
  const double xqx = (double)xq.x, xqy = (double)xq.y;
  const unsigned long long below = (1ull << lane) - 1ull;

  for (int s = 0; s < 64; ++s) {
    float4 p = sx4[(s << 6) + lane];
    int j0 = ((s << 6) + lane) << 1;
    float dx0 = xq.x - p.x, dy0 = xq.y - p.y;
    float dx1 = xq.x - p.z, dy1 = xq.y - p.w;
    float d0 = dx0 * dx0 + dy0 * dy0;
    float d1 = dx1 * dx1 + dy1 * dy1;
    bool c0 = (d0 <= Tpad) && (j0 != q);
    bool c1 = (d1 <= Tpad) && (j0 + 1 != q);
    unsigned long long mk0 = __ballot(c0);
    unsigned long long mk1 = __ballot(c1);
    if (mk0 | mk1) {                               // wave-uniform branch, ~23% taken
      int tot = __popcll(mk0) + __popcll(mk1);
      int base = 0;
      if (lane == 0) base = atomicAdd(&cnt[w], tot);
      base = __shfl(base, 0, 64);
      if (c0) {
        double dx = xqx - (double)p.x, dy = xqy - (double)p.y;   // exact subtractions
        double dd = dx * dx + dy * dy;                           // rel err ~1e-16
        unsigned long long key =
            ((unsigned long long)__double_as_longlong(dd) & ~0x1FFFull) |
            (unsigned long long)j0;                              // tie-break: lower idx
        int o = base + __popcll(mk0 & below);
        if (o < 64) buf[w][o] = key;
      }
      if (c1) {
        double dx = xqx - (double)p.z, dy = xqy - (double)p.w;
        double dd = dx * dx + dy * dy;
        unsigned long long key =
            ((unsigned long long)__double_as_longlong(dd) & ~0x1FFFull) |
            (unsigned long long)(j0 + 1);
        int o = base + __popcll(mk0) + __popcll(mk1 & below);
        if (o < 64) buf[w][o] = key;
      }
    }
  }
  __syncthreads();

  // ---- final: sort collected (>=15 guaranteed, ~17 expected), vote on top-15 ----
  int C = cnt[w];
  C = (C > 64) ? 64 : C;
  unsigned long long kv = (lane < C) ? buf[w][lane] : ~0ull;
  kv = bitonic_sort_u64(kv, lane);
  int jj = (int)(kv & 0x1FFFull);
  int lbl = (int)((ybits[jj >> 5] >> (jj & 31)) & 1u);
  unsigned long long vm = __ballot((lane < KNN) && lbl);
  if (lane == 0) out[q] = (__popcll(vm) >= 8) ? 1.0f : 0.0f;   // sum > 7.5
}

extern "C" void kernel_launch(void* const* d_in, const int* in_sizes, int n_in,
                              void* d_out, int out_size, void* d_ws, size_t ws_size,
                              hipStream_t stream) {
  const float* x = (const float*)d_in[0];
  const int* y = (const int*)d_in[1];
  float* out = (float*)d_out;
  dim3 grid(NPTS / WPB);   // 1024 blocks
  dim3 block(TPB);         // 512 threads = 8 waves
  hipLaunchKernelGGL(knn_kernel, grid, block, 0, stream, x, y, out);
}

// Round 2
// 33.896 us; speedup vs baseline: 1.7273x; 1.7273x over previous
//
#include <hip/hip_runtime.h>

#define NPTS 8192
#define KNN  15
#define QPW  2                // queries per wave
#define WPB  8                // waves per block
#define TPB  (WPB * 64)       // 512 threads

// Ascending bitonic sort of one u32 per lane across a 64-lane wave.
__device__ __forceinline__ unsigned int bitonic_sort_u32(unsigned int v, int lane) {
#pragma unroll
  for (int k = 2; k <= 64; k <<= 1) {
#pragma unroll
    for (int j = k >> 1; j > 0; j >>= 1) {
      unsigned int o = __shfl_xor(v, j, 64);
      bool keep_min = ((lane & k) == 0) == ((lane & j) == 0);
      unsigned int lo = (v < o) ? v : o;
      unsigned int hi = (v < o) ? o : v;
      v = keep_min ? lo : hi;
    }
  }
  return v;
}

// Ascending bitonic sort of one u64 per lane across a 64-lane wave.
__device__ __forceinline__ unsigned long long bitonic_sort_u64(unsigned long long v, int lane) {
#pragma unroll
  for (int k = 2; k <= 64; k <<= 1) {
#pragma unroll
    for (int j = k >> 1; j > 0; j >>= 1) {
      unsigned long long o = __shfl_xor(v, j, 64);
      bool keep_min = ((lane & k) == 0) == ((lane & j) == 0);
      unsigned long long lo = (v < o) ? v : o;
      unsigned long long hi = (v < o) ? o : v;
      v = keep_min ? lo : hi;
    }
  }
  return v;
}

__global__ __launch_bounds__(TPB)
void knn_kernel(const float* __restrict__ x, const int* __restrict__ y,
                float* __restrict__ out) {
  __shared__ float4 sx4[NPTS / 2];                // 64 KB: all points, (x0,y0,x1,y1)
  __shared__ unsigned int ybits[NPTS / 32];       // 1 KB label bitset
  __shared__ unsigned int buf[WPB][QPW][64];      // 4 KB candidate-index buffers
  __shared__ int cnt[WPB][QPW];

  const int tid = threadIdx.x;

  // ---- stage x (coalesced float4) and y (bitset) into LDS ----
  const float4* gx4 = (const float4*)x;
#pragma unroll
  for (int i = tid; i < NPTS / 2; i += TPB) sx4[i] = gx4[i];
  if (tid < NPTS / 32) {
    const int4* yy = (const int4*)(y + (tid << 5));
    unsigned int b = 0;
#pragma unroll
    for (int k2 = 0; k2 < 8; ++k2) {
      int4 v = yy[k2];
      b |= ((unsigned int)(v.x & 1) << (4 * k2)) |
           ((unsigned int)(v.y & 1) << (4 * k2 + 1)) |
           ((unsigned int)(v.z & 1) << (4 * k2 + 2)) |
           ((unsigned int)(v.w & 1) << (4 * k2 + 3));
    }
    ybits[tid] = b;
  }
  if (tid < WPB * QPW) ((int*)cnt)[tid] = 0;
  __syncthreads();

  const int w = tid >> 6;
  const int lane = tid & 63;
  const int q0 = ((int)blockIdx.x * WPB + w) * QPW;   // this wave's two queries
  const float2 xqa = ((const float2*)sx4)[q0];
  const float2 xqb = ((const float2*)sx4)[q0 + 1];

  // ---- pass 1: per-lane min distance per query (self NOT excluded) ----
  float ma = 3.0e38f, mb = 3.0e38f;
#pragma unroll 8
  for (int s = 0; s < 64; ++s) {
    float4 p = sx4[(s << 6) + lane];
    float ax0 = xqa.x - p.x, ay0 = xqa.y - p.y;
    float ax1 = xqa.x - p.z, ay1 = xqa.y - p.w;
    float bx0 = xqb.x - p.x, by0 = xqb.y - p.y;
    float bx1 = xqb.x - p.z, by1 = xqb.y - p.w;
    float d0a = ax0 * ax0 + ay0 * ay0;
    float d1a = ax1 * ax1 + ay1 * ay1;
    float d0b = bx0 * bx0 + by0 * by0;
    float d1b = bx1 * bx1 + by1 * by1;
    ma = fminf(ma, fminf(d0a, d1a));
    mb = fminf(mb, fminf(d0b, d1b));
  }

  // 16th-smallest lane-min (index KNN): 16 distinct candidates <= T, at most
  // one is self => >=15 non-self => T >= true 15th NN distance. (Self has d=0,
  // it may replace one lane's min, hence 16th not 15th.)
  unsigned int sa = bitonic_sort_u32(__float_as_uint(ma), lane);
  unsigned int sb = bitonic_sort_u32(__float_as_uint(mb), lane);
  const float Ta = __uint_as_float(__shfl(sa, KNN, 64)) * (1.0f + 1.0e-5f) + 1.0e-30f;
  const float Tb = __uint_as_float(__shfl(sb, KNN, 64)) * (1.0f + 1.0e-5f) + 1.0e-30f;

  // ---- pass 2: compact indices of candidates with d32 <= T (incl. self) ----
#pragma unroll 4
  for (int s = 0; s < 64; ++s) {
    float4 p = sx4[(s << 6) + lane];
    int j0 = ((s << 6) + lane) << 1;
    float ax0 = xqa.x - p.x, ay0 = xqa.y - p.y;
    float ax1 = xqa.x - p.z, ay1 = xqa.y - p.w;
    float bx0 = xqb.x - p.x, by0 = xqb.y - p.y;
    float bx1 = xqb.x - p.z, by1 = xqb.y - p.w;
    float d0a = ax0 * ax0 + ay0 * ay0;
    float d1a = ax1 * ax1 + ay1 * ay1;
    float d0b = bx0 * bx0 + by0 * by0;
    float d1b = bx1 * bx1 + by1 * by1;
    if (d0a <= Ta) { int o = atomicAdd(&cnt[w][0], 1); if (o < 64) buf[w][0][o] = (unsigned)j0; }
    if (d1a <= Ta) { int o = atomicAdd(&cnt[w][0], 1); if (o < 64) buf[w][0][o] = (unsigned)(j0 + 1); }
    if (d0b <= Tb) { int o = atomicAdd(&cnt[w][1], 1); if (o < 64) buf[w][1][o] = (unsigned)j0; }
    if (d1b <= Tb) { int o = atomicAdd(&cnt[w][1], 1); if (o < 64) buf[w][1][o] = (unsigned)(j0 + 1); }
  }
  __syncthreads();

  // ---- final: exact fp64 keys for the ~19 survivors, sort, vote ----
#pragma unroll
  for (int qi = 0; qi < QPW; ++qi) {
    const int q = q0 + qi;
    const float2 xq = (qi == 0) ? xqa : xqb;
    int C = cnt[w][qi];
    C = (C > 64) ? 64 : C;
    unsigned long long kv = ~0ull;
    if (lane < C) {
      int jj = (int)buf[w][qi][lane];
      float2 pj = ((const float2*)sx4)[jj];
      double dx = (double)xq.x - (double)pj.x;       // exact (fp32 -> fp64)
      double dy = (double)xq.y - (double)pj.y;
      double dd = dx * dx + dy * dy;                 // rel err ~1e-16
      kv = ((unsigned long long)__double_as_longlong(dd) & ~0x1FFFull) |
           (unsigned long long)jj;                   // tie-break: lower index
      if (jj == q) kv = ~0ull;                       // drop self
    }
    kv = bitonic_sort_u64(kv, lane);
    int jj = (int)(kv & 0x1FFFull);
    int lbl = (int)((ybits[jj >> 5] >> (jj & 31)) & 1u);
    unsigned long long vm = __ballot((lane < KNN) && lbl);
    if (lane == 0) out[q] = (__popcll(vm) >= 8) ? 1.0f : 0.0f;   // sum > 7.5
  }
}

extern "C" void kernel_launch(void* const* d_in, const int* in_sizes, int n_in,
                              void* d_out, int out_size, void* d_ws, size_t ws_size,
                              hipStream_t stream) {
  const float* x = (const float*)d_in[0];
  const int* y = (const int*)d_in[1];
  float* out = (float*)d_out;
  dim3 grid(NPTS / (WPB * QPW));   // 512 blocks
  dim3 block(TPB);                 // 512 threads = 8 waves
  hipLaunchKernelGGL(knn_kernel, grid, block, 0, stream, x, y, out);
}